// Round 3
// baseline (1256.000 us; speedup 1.0000x reference)
//
#include <hip/hip_runtime.h>
#include <math.h>

// PQLayer forward, MI355X — R3.
//   x:     (B, 512) fp32      d_in[0]
//   C:     (64, 256, 8) fp32  d_in[1]
//   out0:  x_hat (B, 512) fp32     = C[m, k*, :]
//   out1:  codes (B, 64, 256) fp32 = one_hot(k*)    [1.07 GB -> dominates]
//
// R3 structure:
//  - pq_argmax: C[m] read via wave/block-UNIFORM global pointer -> compiler
//    scalarizes to s_load (SMEM pipe), VALU does only the np-exact dot tree.
//    bestk stored transposed [m][b] -> one coalesced 64 B line per wave.
//  - pq_write: fill-shaped. Each block owns 4 consecutive b-rows (256 KB of
//    codes): bare float4 zero stores (fillBufferAligned-identical inst mix,
//    which measures 6.25 TB/s), __syncthreads (drains vmcnt(0) -> zero stores
//    committed to L2), then 256 single-dword 1.0 pokes into its OWN slab.
//    xhat written coalesced from L2-hot C.

#define B_SZ   16384
#define FEAT   512
#define M_SZ   64
#define K_SZ   256
#define D_SZ   8

// ---------------- Kernel 1: argmax ----------------
// grid: 64 m * 64 chunks = 4096 blocks of 256; thread = one b.
__global__ __launch_bounds__(256) void pq_argmax(
    const float* __restrict__ x,
    const float* __restrict__ C,
    unsigned char* __restrict__ bestk8)   // [M][B] transposed
{
#pragma clang fp contract(off)   // np einsum: separate product roundings, no FMA

    const int m     = blockIdx.x & (M_SZ - 1);   // block-uniform
    const int chunk = blockIdx.x >> 6;
    const int b     = (chunk << 8) | threadIdx.x;

    const float* xp = x + (size_t)b * FEAT + m * D_SZ;
    const float4 xa = *(const float4*)(xp);
    const float4 xb = *(const float4*)(xp + 4);

    const float* __restrict__ Cm = C + (size_t)m * (K_SZ * D_SZ);

    float best  = -INFINITY;
    int   bestk = 0;

#pragma unroll 8
    for (int k = 0; k < K_SZ; ++k) {
        const float* cr = Cm + k * D_SZ;   // uniform addr -> s_load path
        float s0 = xa.x * cr[0];
        float s1 = xa.y * cr[1];
        float s2 = xa.z * cr[2];
        float s3 = xa.w * cr[3];
        float s4 = xb.x * cr[4];
        float s5 = xb.y * cr[5];
        float s6 = xb.z * cr[6];
        float s7 = xb.w * cr[7];
        float t0 = s0 + s4;                // np SSE pairwise tree
        float t1 = s1 + s5;
        float t2 = s2 + s6;
        float t3 = s3 + s7;
        float dot = (t0 + t1) + (t2 + t3);
        if (dot > best) { best = dot; bestk = k; }  // strict >: first max = np.argmax
    }

    // coalesced: wave writes 64 consecutive bytes
    bestk8[(size_t)m * B_SZ + b] = (unsigned char)bestk;
}

// ---------------- Kernel 2: fill-shaped writer ----------------
// 4096 blocks of 256; block owns b rows [4*blk, 4*blk+4).
__global__ __launch_bounds__(256) void pq_write(
    const float* __restrict__ C,
    const unsigned char* __restrict__ bestk8,  // [M][B]
    float* __restrict__ xhat,
    float* __restrict__ codes)
{
    const int t    = threadIdx.x;
    const int b0   = blockIdx.x << 2;      // first of 4 rows
    const int r    = t >> 6;               // 0..3
    const int lane = t & 63;               // = m
    const int b    = b0 + r;

    // this thread's (b, m=lane) code index
    const int kb = (int)bestk8[(size_t)lane * B_SZ + b];

    // ---- xhat[b, lane*8 ..] = C[lane, kb, :]  (gather, C is L1/L2-hot) ----
    {
        const float* cw = C + ((size_t)lane * K_SZ + kb) * D_SZ;
        const float4 h0 = ((const float4*)cw)[0];
        const float4 h1 = ((const float4*)cw)[1];
        float* xh = xhat + (size_t)b * FEAT + lane * D_SZ;
        ((float4*)xh)[0] = h0;
        ((float4*)xh)[1] = h1;
    }

    // ---- zero the block's 256 KB codes slab: bare float4 stores ----
    {
        const float4 z = {0.f, 0.f, 0.f, 0.f};
        float4* slab = (float4*)(codes + (size_t)b0 * (M_SZ * K_SZ));
        // 4 rows * 16384 floats = 16384 float4; 256 threads -> 64 iters
#pragma unroll 8
        for (int i = t; i < 16384; i += 256) slab[i] = z;
    }

    __syncthreads();   // drains vmcnt(0): zeros committed before pokes

    // ---- poke the ones: one dword per (b, m) pair owned by this block ----
    codes[((size_t)b * M_SZ + lane) * K_SZ + kb] = 1.0f;
}

extern "C" void kernel_launch(void* const* d_in, const int* in_sizes, int n_in,
                              void* d_out, int out_size, void* d_ws, size_t ws_size,
                              hipStream_t stream)
{
    const float* x = (const float*)d_in[0];
    const float* C = (const float*)d_in[1];
    float* xhat  = (float*)d_out;                           // (B, 512)
    float* codes = (float*)d_out + (size_t)B_SZ * FEAT;     // (B, 64, 256)
    unsigned char* bestk8 = (unsigned char*)d_ws;           // [M][B] u8 = 1 MB

    hipLaunchKernelGGL(pq_argmax, dim3(4096), dim3(256), 0, stream, x, C, bestk8);
    hipLaunchKernelGGL(pq_write,  dim3(4096), dim3(256), 0, stream, C, bestk8, xhat, codes);
}

// Round 4
// 1204.566 us; speedup vs baseline: 1.0427x; 1.0427x over previous
//
#include <hip/hip_runtime.h>
#include <math.h>

// PQLayer forward, MI355X — R4.
//   x:     (B, 512) fp32      d_in[0]
//   C:     (64, 256, 8) fp32  d_in[1]
//   out0:  x_hat (B, 512) fp32     = C[m, k*, :]
//   out1:  codes (B, 64, 256) fp32 = one_hot(k*)    [1.07 GB write dominates]
//
// Measurement model (R1 evidence: single kernel < 707us per rocprof, yet
// dur_us = 1273): dur_us includes the harness's ~707us 0xAA poison fill.
// Addressable time = dur_us - 707. R3 addressable ~549us vs ~250us floor.
//
// R4:
//  K1 pq_argmax — np-exact dot tree (contract off), C via wave-uniform global
//     reads (s_load path), bestk stored [B][M] (one byte per (b,m); L2 merges).
//     XCD swizzle: the 4 m-blocks sharing each 128B x-line go to one XCD.
//  K2 pq_fill   — SINGLE-PASS fill-with-ones. Shaped like rocclr fill
//     (proven 6.25 TB/s): 64 bare float4 stores/thread, one-hot folded into
//     the stream (k-offset of each float4 is 4*lane = constant; bestk byte is
//     wave-uniform per step, from a 256 B LDS stage). No sync-drain, no RMW.
//     xhat written coalesced (lane = m) from L2-hot C.

#define B_SZ   16384
#define FEAT   512
#define M_SZ   64
#define K_SZ   256
#define D_SZ   8

// ---------------- K1: argmax ----------------
// 4096 blocks x 256 threads; block = (m, chunk of 256 b), thread = one b.
__global__ __launch_bounds__(256) void pq_argmax(
    const float* __restrict__ x,
    const float* __restrict__ C,
    unsigned char* __restrict__ bestk8)   // [B][M]
{
#pragma clang fp contract(off)   // np einsum: separate product roundings, no FMA

    // XCD swizzle: blocks with same (chunk, m>>2) share x cache lines; give
    // them blockIdx === (mod 8) so they land on the same XCD's L2.
    // idx = (g>>3)*32 + mm*8 + (g&7), g = chunk*16 + (m>>2), mm = m&3.
    const int idx  = blockIdx.x;
    const int g    = ((idx >> 5) << 3) | (idx & 7);
    const int mm   = (idx >> 3) & 3;
    const int m    = ((g & 15) << 2) | mm;     // block-uniform
    const int chunk = g >> 4;
    const int b    = (chunk << 8) | threadIdx.x;

    const float* xp = x + (size_t)b * FEAT + m * D_SZ;
    const float4 xa = ((const float4*)xp)[0];
    const float4 xb = ((const float4*)xp)[1];

    const float* __restrict__ Cm = C + (size_t)m * (K_SZ * D_SZ);

    float best  = -INFINITY;
    int   bestk = 0;

#pragma unroll 8
    for (int k = 0; k < K_SZ; ++k) {
        const float* cr = Cm + k * D_SZ;   // uniform addr -> SMEM/s_load path
        float s0 = xa.x * cr[0];
        float s1 = xa.y * cr[1];
        float s2 = xa.z * cr[2];
        float s3 = xa.w * cr[3];
        float s4 = xb.x * cr[4];
        float s5 = xb.y * cr[5];
        float s6 = xb.z * cr[6];
        float s7 = xb.w * cr[7];
        float t0 = s0 + s4;                // np SSE pairwise tree
        float t1 = s1 + s5;
        float t2 = s2 + s6;
        float t3 = s3 + s7;
        float dot = (t0 + t1) + (t2 + t3);
        if (dot > best) { best = dot; bestk = k; }  // strict >: first max = np.argmax
    }

    // [B][M] byte scatter (stride 64); 1 MB region stays L2-resident -> merges
    bestk8[(size_t)b * M_SZ + m] = (unsigned char)bestk;
}

// ---------------- K2: single-pass fill-with-ones + xhat ----------------
// 4096 blocks x 256 threads; block owns b rows [4*blk, 4*blk+4) = 256 KB slab.
__global__ __launch_bounds__(256) void pq_fill(
    const float* __restrict__ C,
    const unsigned char* __restrict__ bestk8,  // [B][M]
    float* __restrict__ xhat,
    float* __restrict__ codes)
{
    const int t    = threadIdx.x;
    const int b0   = blockIdx.x << 2;
    const int w    = t >> 6;         // wave 0..3
    const int lane = t & 63;

    __shared__ unsigned char lbk[4 * M_SZ];   // block's 256 bestk bytes

    // stage bestk (4 rows x 64 m = 256 B, L2-hot)
    lbk[t] = bestk8[(size_t)b0 * M_SZ + t];

    // ---- xhat: wave w -> row b0+w, lane -> m. Coalesced 2KB/wave. ----
    {
        const int b  = b0 + w;
        const int kb = (int)bestk8[(size_t)b * M_SZ + lane];
        const float* cw = C + ((size_t)lane * K_SZ + kb) * D_SZ;
        const float4 h0 = ((const float4*)cw)[0];
        const float4 h1 = ((const float4*)cw)[1];
        float* xh = xhat + (size_t)b * FEAT + lane * D_SZ;
        ((float4*)xh)[0] = h0;
        ((float4*)xh)[1] = h1;
    }

    __syncthreads();   // lbk visible

    // ---- codes slab: 64 float4 stores/thread, one-hot folded in-stream ----
    // float4 index i = t + 256*j:
    //   row r       = j >> 4                (wave-uniform)
    //   m           = ((t>>6) + 4*j) & 63   (wave-uniform)
    //   k-offset    = 4*(t & 63)            (constant per thread)
    const int lane4 = lane << 2;
    float4* const slab = (float4*)(codes + (size_t)b0 * (M_SZ * K_SZ));

#pragma unroll 4
    for (int j = 0; j < 64; ++j) {
        const int r  = j >> 4;
        const int mj = (w + 4 * j) & 63;
        const int kk = (int)lbk[(r << 6) | mj];   // LDS broadcast (uniform)
        float4 v;
        v.x = (kk == lane4 + 0) ? 1.0f : 0.0f;
        v.y = (kk == lane4 + 1) ? 1.0f : 0.0f;
        v.z = (kk == lane4 + 2) ? 1.0f : 0.0f;
        v.w = (kk == lane4 + 3) ? 1.0f : 0.0f;
        slab[t + 256 * j] = v;
    }
}

extern "C" void kernel_launch(void* const* d_in, const int* in_sizes, int n_in,
                              void* d_out, int out_size, void* d_ws, size_t ws_size,
                              hipStream_t stream)
{
    const float* x = (const float*)d_in[0];
    const float* C = (const float*)d_in[1];
    float* xhat  = (float*)d_out;                           // (B, 512)
    float* codes = (float*)d_out + (size_t)B_SZ * FEAT;     // (B, 64, 256)
    unsigned char* bestk8 = (unsigned char*)d_ws;           // [B][M] u8 = 1 MB

    hipLaunchKernelGGL(pq_argmax, dim3(4096), dim3(256), 0, stream, x, C, bestk8);
    hipLaunchKernelGGL(pq_fill,   dim3(4096), dim3(256), 0, stream, C, bestk8, xhat, codes);
}